// Round 11
// baseline (115.187 us; speedup 1.0000x reference)
//
#include <hip/hip_runtime.h>
#include <math.h>

#define BATCH 16
#define CH 320

typedef __attribute__((ext_vector_type(8))) short bf16x8;
typedef __attribute__((ext_vector_type(4))) float f32x4;

union FragU { bf16x8 f; unsigned long long u[2]; };

// ---------------- workspace layout (floats) ----------------
static constexpr size_t PLSZ     = (size_t)BATCH * CH * 64;      // 327680
static constexpr size_t WS_POOL3 = 0;                            // 3*PLSZ (U overlaps later)
static constexpr size_t WS_POOL4 = 3 * PLSZ;
static constexpr size_t WS_TF    = 6 * PLSZ;
static constexpr size_t WS_MEANS = 9 * PLSZ;                     // 2949120
static constexpr size_t WS_AW    = WS_MEANS + 9 * BATCH * CH;    // +46080
static constexpr size_t WS_PART  = WS_AW + 144;
static constexpr size_t WS_ABF   = WS_PART + 3 * BATCH * 80 * 64; // bf16 A, 983040 shorts
// V buffers (bf16 shorts) overlap POOL3/POOL4/TF (dead by GEMM time). Layout [b][x][64p].
static constexpr size_t UB3 = 0;
static constexpr size_t UB4 = (size_t)BATCH * 4096 * 64;         // 4194304
static constexpr size_t UB5 = UB4 + (size_t)BATCH * 1024 * 64;   // 5242880

__device__ __forceinline__ float bf2f(unsigned short u) {
    union { unsigned int i; float f; } x; x.i = ((unsigned int)u) << 16; return x.f;
}
__device__ __forceinline__ unsigned short f2bf(float f) {
    union { float f; unsigned int i; } x; x.f = f;
    return (unsigned short)((x.i + 0x7FFFu + ((x.i >> 16) & 1u)) >> 16);
}
__device__ __forceinline__ unsigned cvtpk(float lo, float hi) {
    unsigned r;
    asm("v_cvt_pk_bf16_f32 %0, %1, %2" : "=v"(r) : "v"(lo), "v"(hi));
    return r;
}

// ---------------- 1) fused pool(p3)+pool(p4)+mean(p5) ----------------
template <int HW, int KK>
__device__ __forceinline__ void pool_body(int idx, const float* __restrict__ a0,
                                          const float* __restrict__ a1, const float* __restrict__ a2,
                                          float* __restrict__ dst, float* __restrict__ means, int lane) {
    constexpr int NPL = BATCH * CH * 64;
    int tmpl = idx / NPL;
    int r = idx % NPL;
    const float* src = (tmpl == 0) ? a0 : ((tmpl == 1) ? a1 : a2);
    int bc = r >> 6;
    int pos = r & 63;
    int oh = pos >> 3, ow = pos & 7;
    const float* base = src + (size_t)bc * HW * HW;
    float s = 0.0f;
    if constexpr (KK == 4) {
#pragma unroll
        for (int i = 0; i < 4; ++i) {
            float4 v = *(const float4*)(base + (oh * 4 + i) * HW + ow * 4);
            s += v.x + v.y + v.z + v.w;
        }
    } else {
#pragma unroll
        for (int i = 0; i < 2; ++i) {
            float2 v = *(const float2*)(base + (oh * 2 + i) * HW + ow * 2);
            s += v.x + v.y;
        }
    }
    s *= (1.0f / (KK * KK));
    dst[idx] = s;
    float m = s;
#pragma unroll
    for (int o = 32; o; o >>= 1) m += __shfl_xor(m, o);
    if (lane == 0) means[tmpl * (BATCH * CH) + bc] = m * (1.0f / 64.0f);
}

__global__ __launch_bounds__(256) void prep_kernel(
    const float* __restrict__ t0p3, const float* __restrict__ t1p3, const float* __restrict__ t2p3,
    const float* __restrict__ t0p4, const float* __restrict__ t1p4, const float* __restrict__ t2p4,
    const float* __restrict__ t0p5, const float* __restrict__ t1p5, const float* __restrict__ t2p5,
    float* __restrict__ pool3, float* __restrict__ pool4, float* __restrict__ means) {
    int bid = blockIdx.x, t = threadIdx.x, lane = t & 63;
    if (bid < 3840) {
        pool_body<32, 4>(bid * 256 + t, t0p3, t1p3, t2p3, pool3, means, lane);
    } else if (bid < 7680) {
        pool_body<16, 2>((bid - 3840) * 256 + t, t0p4, t1p4, t2p4, pool4, means + 3 * BATCH * CH, lane);
    } else {
        int w = ((bid - 7680) * 256 + t) >> 6;
        constexpr int NR = BATCH * CH;
        int tmpl = w / NR, rem = w % NR;
        const float* src = (tmpl == 0) ? t0p5 : ((tmpl == 1) ? t1p5 : t2p5);
        float v = src[(size_t)rem * 64 + lane];
#pragma unroll
        for (int o = 32; o; o >>= 1) v += __shfl_xor(v, o);
        if (lane == 0) means[6 * BATCH * CH + w] = v * (1.0f / 64.0f);
    }
}

// ---------------- 2) fusion weights ----------------
__global__ __launch_bounds__(256) void weights_kernel(const float* __restrict__ means,
        const float* w13, const float* b13, const float* w23, const float* b23,
        const float* w14, const float* b14, const float* w24, const float* b24,
        const float* w15, const float* b15, const float* w25, const float* b25,
        float* __restrict__ a_out) {
    __shared__ float m[3 * CH];
    __shared__ float hv[240];
    __shared__ float sc[3];
    int lvl = blockIdx.x / BATCH;
    int b = blockIdx.x % BATCH;
    int t = threadIdx.x;
    const float* w1 = (lvl == 0) ? w13 : ((lvl == 1) ? w14 : w15);
    const float* b1 = (lvl == 0) ? b13 : ((lvl == 1) ? b14 : b15);
    const float* w2 = (lvl == 0) ? w23 : ((lvl == 1) ? w24 : w25);
    const float* b2 = (lvl == 0) ? b23 : ((lvl == 1) ? b24 : b25);
    const float* mb = means + lvl * (3 * BATCH * CH);
    for (int j = t; j < 3 * CH; j += 256) {
        int i = j / CH, c = j % CH;
        m[j] = mb[i * (BATCH * CH) + b * CH + c];
    }
    __syncthreads();
    if (t < 240) {
        int i = t / 80, jj = t % 80;
        float acc = b1[jj];
#pragma unroll 4
        for (int c = 0; c < CH; ++c) acc = fmaf(m[i * CH + c], w1[c * 80 + jj], acc);
        hv[t] = fmaxf(acc, 0.0f) * w2[jj];
    }
    __syncthreads();
    if (t < 3) {
        float s = b2[0];
#pragma unroll 8
        for (int jj = 0; jj < 80; ++jj) s += hv[t * 80 + jj];
        sc[t] = s;
    }
    __syncthreads();
    if (t == 0) {
        float mx = fmaxf(sc[0], fmaxf(sc[1], sc[2]));
        float e0 = expf(sc[0] - mx), e1 = expf(sc[1] - mx), e2 = expf(sc[2] - mx);
        float inv = 1.0f / (e0 + e1 + e2);
        float* ao = a_out + lvl * 48 + b * 3;
        ao[0] = e0 * inv; ao[1] = e1 * inv; ao[2] = e2 * inv;
    }
}

// ---------------- 3a) fuse templates + partial sum of squares ----------------
__global__ __launch_bounds__(256) void fuse_kernel(
        const float* __restrict__ p30, const float* __restrict__ p31, const float* __restrict__ p32,
        const float* __restrict__ p40, const float* __restrict__ p41, const float* __restrict__ p42,
        const float* __restrict__ p50, const float* __restrict__ p51, const float* __restrict__ p52,
        const float* __restrict__ aw, float* __restrict__ tf, float* __restrict__ partial) {
    __shared__ float red[256];
    int lvl = blockIdx.x / 1280;
    int r = blockIdx.x % 1280;
    int t = threadIdx.x;
    const float* p0 = (lvl == 0) ? p30 : ((lvl == 1) ? p40 : p50);
    const float* p1 = (lvl == 0) ? p31 : ((lvl == 1) ? p41 : p51);
    const float* p2 = (lvl == 0) ? p32 : ((lvl == 1) ? p42 : p52);
    int idx = r * 256 + t;
    int b = r / 80;
    int j = r % 80;
    const float* ab = aw + lvl * 48 + b * 3;
    float a0 = ab[0], a1 = ab[1], a2 = ab[2];
    float v = a0 * p0[idx] + a1 * p1[idx] + a2 * p2[idx];
    tf[(size_t)lvl * PLSZ + idx] = v;
    red[t] = v * v;
    __syncthreads();
    if (t < 64) {
        float s = red[t] + red[t + 64] + red[t + 128] + red[t + 192];
        partial[((size_t)(lvl * BATCH + b) * 80 + j) * 64 + t] = s;
    }
}

// ---------------- 3b) finalize sinv + transpose + scale -> bf16 A [lvl][b][p][c] ----------------
__global__ __launch_bounds__(256) void atrans_kernel(const float* __restrict__ tf,
        const float* __restrict__ part, short* __restrict__ abf) {
    __shared__ float lds[64 * 68];
    __shared__ float red2[4 * 64];
    __shared__ float sv[64];
    int lvl = blockIdx.x >> 4;
    int b = blockIdx.x & 15;
    int t = threadIdx.x;
    {
        const float* p = part + ((size_t)(lvl * BATCH + b) * 80) * 64 + (t & 63);
        int jg = t >> 6;
        float s = 0.0f;
        for (int j = jg * 20; j < jg * 20 + 20; ++j) s += p[j * 64];
        red2[jg * 64 + (t & 63)] = s;
    }
    __syncthreads();
    if (t < 64) {
        float s = red2[t] + red2[64 + t] + red2[128 + t] + red2[192 + t];
        sv[t] = 1.0f / fmaxf(sqrtf(s), 1e-12f);
    }
    __syncthreads();
    const float* tb = tf + (size_t)lvl * PLSZ + (size_t)b * (CH * 64);
    short* ab = abf + ((size_t)(lvl * BATCH + b) * 64) * 320;
    for (int c0 = 0; c0 < 320; c0 += 64) {
        __syncthreads();
#pragma unroll
        for (int i = 0; i < 4; ++i) {
            int c = (t >> 4) + 16 * i;
            int p4 = (t & 15) * 4;
            *(float4*)(lds + c * 68 + p4) = *(const float4*)(tb + (size_t)(c0 + c) * 64 + p4);
        }
        __syncthreads();
        int p = t >> 2;
        int cs = (t & 3) * 16;
        float s_p = sv[p];
        bf16x8 o0, o1;
#pragma unroll
        for (int u = 0; u < 8; ++u) o0[u] = (short)f2bf(lds[(cs + u) * 68 + p] * s_p);
#pragma unroll
        for (int u = 0; u < 8; ++u) o1[u] = (short)f2bf(lds[(cs + 8 + u) * 68 + p] * s_p);
        *(bf16x8*)(ab + (size_t)p * 320 + c0 + cs) = o0;
        *(bf16x8*)(ab + (size_t)p * 320 + c0 + cs + 8) = o1;
    }
}

// ---------------- 4) swapped-operand MFMA GEMM, x-tile 128, 3 blocks/CU (MLP diet) ----------------
// V[b][x][p] = inv[x] * sum_c T[p][c] * S[b][c][x]
// R10 structure; VGPR diet for 3 blocks/CU: no T double-buffer (tcur loaded at step start,
// oldest VMEM op -> counted wait leaves S-prefetch in flight), placeholder tr-reads removed.
template <int N>
__device__ __forceinline__ void gemm_body(const float* __restrict__ S, const short* __restrict__ T,
                                          short* __restrict__ V, int bid, unsigned short* St) {
    constexpr int XB = N / 128;
    int b = bid / XB;
    int x0b = (bid % XB) * 128;
    int t = threadIdx.x;
    int w = t >> 6, l = t & 63, g = l >> 4, ln = l & 15;
    int fidx = t & 31;                 // x float4-chunk (x = fidx*4, in [0,128))
    int rg = t >> 5;                   // 0..7 row group (c ≡ rg mod 8)

    const float* Sp = S + (size_t)b * CH * N + x0b + fidx * 4;
    const short* Tb = T + (size_t)b * 64 * 320;

    f32x4 acc[2][4];
#pragma unroll
    for (int i = 0; i < 2; ++i)
#pragma unroll
        for (int j = 0; j < 4; ++j) acc[i][j] = (f32x4){0.f, 0.f, 0.f, 0.f};
    float ssq[4] = {0.f, 0.f, 0.f, 0.f};

    // staging LDS offset (shorts), validated subtile map per 64-x half:
    // E(c = rg+8i, x = fidx*4..) = ebase + i*128
    int ebase = (fidx >> 4) * 2048 + (((fidx >> 2) & 3) * 8 + (rg >> 2)) * 64 + (rg & 3) * 16 + (fidx & 3) * 4;
    // tr-read lane base (bytes): half (w>>1), 16x-group (w&1)*2+mt (mt at +1024), validated map
    unsigned trbase = (unsigned)(size_t)St + (unsigned)((w >> 1) * 4096 + (w & 1) * 2048 + g * 256 + ln * 8);

#define LOADR(DST, S_) { \
    _Pragma("unroll") \
    for (int i = 0; i < 4; ++i) \
        DST[i] = *(const float4*)(Sp + (size_t)(32 * (S_) + rg + 8 * i) * N); }

#define LOADT(DST, S_) { \
    _Pragma("unroll") \
    for (int j = 0; j < 4; ++j) \
        DST[j] = *(const bf16x8*)(Tb + (size_t)(j * 16 + ln) * 320 + 32 * (S_) + 8 * g); }

#define STAGE(SRC, BUF) { \
    _Pragma("unroll") \
    for (int i = 0; i < 4; ++i) { \
        float4 v = SRC[i]; \
        ssq[0] = fmaf(v.x, v.x, ssq[0]); ssq[1] = fmaf(v.y, v.y, ssq[1]); \
        ssq[2] = fmaf(v.z, v.z, ssq[2]); ssq[3] = fmaf(v.w, v.w, ssq[3]); \
        *(uint2*)(St + (BUF) * 4096 + ebase + i * 128) = (uint2){cvtpk(v.x, v.y), cvtpk(v.z, v.w)}; \
    } }

#define TRRD2(FR, OFF) \
    asm volatile("ds_read_b64_tr_b16 %0, %2 offset:%c3\n\tds_read_b64_tr_b16 %1, %2 offset:%c4" \
                 : "=v"((FR).u[0]), "=v"((FR).u[1]) : "v"(trbase), "i"(OFF), "i"((OFF) + 128));

    // ---- prologue: load + stage step 0 ----
    {
        float4 pv[4];
        LOADR(pv, 0)
        STAGE(pv, 0)
    }
    __syncthreads();

#pragma unroll
    for (int s = 0; s < 10; ++s) {
        const int cur = s & 1;
        // T fragments for this step: issued FIRST (oldest) so the counted vmcnt wait at
        // the MFMAs leaves the 4 S-prefetch loads in flight. L2-hot (~200cy).
        bf16x8 tcur[4];
        LOADT(tcur, s)
        float4 nv[4];
        if (s < 9) { LOADR(nv, s + 1) }
        // A-fragments from buf[cur] via hardware-transpose reads (compile-time offsets)
        FragU fa0, fa1;
        if (cur == 0) { TRRD2(fa0, 0)    TRRD2(fa1, 1024) }
        else          { TRRD2(fa0, 8192) TRRD2(fa1, 8192 + 1024) }
        asm volatile("s_waitcnt lgkmcnt(0)" ::: "memory");
        __builtin_amdgcn_sched_barrier(0);
        __builtin_amdgcn_s_setprio(1);
        acc[0][0] = __builtin_amdgcn_mfma_f32_16x16x32_bf16(fa0.f, tcur[0], acc[0][0], 0, 0, 0);
        acc[0][1] = __builtin_amdgcn_mfma_f32_16x16x32_bf16(fa0.f, tcur[1], acc[0][1], 0, 0, 0);
        acc[0][2] = __builtin_amdgcn_mfma_f32_16x16x32_bf16(fa0.f, tcur[2], acc[0][2], 0, 0, 0);
        acc[0][3] = __builtin_amdgcn_mfma_f32_16x16x32_bf16(fa0.f, tcur[3], acc[0][3], 0, 0, 0);
        acc[1][0] = __builtin_amdgcn_mfma_f32_16x16x32_bf16(fa1.f, tcur[0], acc[1][0], 0, 0, 0);
        acc[1][1] = __builtin_amdgcn_mfma_f32_16x16x32_bf16(fa1.f, tcur[1], acc[1][1], 0, 0, 0);
        acc[1][2] = __builtin_amdgcn_mfma_f32_16x16x32_bf16(fa1.f, tcur[2], acc[1][2], 0, 0, 0);
        acc[1][3] = __builtin_amdgcn_mfma_f32_16x16x32_bf16(fa1.f, tcur[3], acc[1][3], 0, 0, 0);
        __builtin_amdgcn_s_setprio(0);
        if (s < 9) { STAGE(nv, cur ^ 1) }
        __syncthreads();
    }
#undef TRRD2
#undef STAGE
#undef LOADT
#undef LOADR

    // ---- per-x inverse search norms (alias dead LDS as floats) ----
    float* Sf = (float*)St;
    *(f32x4*)(Sf + rg * 128 + fidx * 4) = (f32x4){ssq[0], ssq[1], ssq[2], ssq[3]};
    __syncthreads();
    float invv = 0.0f;
    if (t < 128) {
        float s = 0.0f;
#pragma unroll
        for (int i = 0; i < 8; ++i) s += Sf[i * 128 + t];
        invv = 1.0f / fmaxf(sqrtf(s), 1e-12f);
    }
    __syncthreads();
    if (t < 128) Sf[1024 + t] = invv;
    __syncthreads();

    // ---- V write: wave w covers x = w*32 + mt*16 + 4g + r, ALL p (full 128B lines) ----
#pragma unroll
    for (int mt = 0; mt < 2; ++mt) {
#pragma unroll
        for (int r = 0; r < 4; ++r) {
            int xl = w * 32 + mt * 16 + 4 * g + r;
            float iv = Sf[1024 + xl];
            short* vp = V + ((size_t)b * N + x0b + xl) * 64 + ln;
            vp[0]  = (short)f2bf(acc[mt][0][r] * iv);
            vp[16] = (short)f2bf(acc[mt][1][r] * iv);
            vp[32] = (short)f2bf(acc[mt][2][r] * iv);
            vp[48] = (short)f2bf(acc[mt][3][r] * iv);
        }
    }
}

__global__ __launch_bounds__(256, 3) void gemm_kernel(const float* __restrict__ sp3,
        const float* __restrict__ sp4, const float* __restrict__ sp5,
        const short* __restrict__ abf, short* __restrict__ u) {
    __shared__ unsigned short St[2 * 4096];   // 16KB double buffer (epilogue aliases it)
    int bid = blockIdx.x;
    if (bid < 512)      gemm_body<4096>(sp3, abf,          u + UB3, bid,       St);
    else if (bid < 640) gemm_body<1024>(sp4, abf + 327680, u + UB4, bid - 512, St);
    else                gemm_body<256>(sp5, abf + 655360,  u + UB5, bid - 640, St);
}

// ---------------- 5) combine: out[oh][ow] = sum_{kh,kw} V[(oh+kh)*H+ow+kw][kh*8+kw] ----------------
__global__ __launch_bounds__(256) void combine_kernel(const short* __restrict__ U,
                                                      float* __restrict__ out) {
    int tid = blockIdx.x * 256 + threadIdx.x;
    if (tid < 51984) {
        int b = tid / 3249, r = tid % 3249;
        int oh = r / 57, ow = r % 57;
        const short* u = U + UB3 + ((size_t)b * 4096 + oh * 64 + ow) * 64;
        float s = 0.0f;
#pragma unroll
        for (int kh = 0; kh < 8; ++kh)
#pragma unroll
            for (int kw = 0; kw < 8; ++kw)
                s += bf2f((unsigned short)u[(kh * 64 + kw) * 64 + kh * 8 + kw]);
        out[tid] = s;
    } else if (tid < 61984) {
        int x = tid - 51984;
        int b = x / 625, r = x % 625;
        int oh = r / 25, ow = r % 25;
        const short* u = U + UB4 + ((size_t)b * 1024 + oh * 32 + ow) * 64;
        float s = 0.0f;
#pragma unroll
        for (int kh = 0; kh < 8; ++kh)
#pragma unroll
            for (int kw = 0; kw < 8; ++kw)
                s += bf2f((unsigned short)u[(kh * 32 + kw) * 64 + kh * 8 + kw]);
        out[tid] = s;
    } else if (tid < 63280) {
        int x = tid - 61984;
        int b = x / 81, r = x % 81;
        int oh = r / 9, ow = r % 9;
        const short* u = U + UB5 + ((size_t)b * 256 + oh * 16 + ow) * 64;
        float s = 0.0f;
#pragma unroll
        for (int kh = 0; kh < 8; ++kh)
#pragma unroll
            for (int kw = 0; kw < 8; ++kw)
                s += bf2f((unsigned short)u[(kh * 16 + kw) * 64 + kh * 8 + kw]);
        out[tid] = s;
    }
}

extern "C" void kernel_launch(void* const* d_in, const int* in_sizes, int n_in,
                              void* d_out, int out_size, void* d_ws, size_t ws_size,
                              hipStream_t stream) {
    const float* t0p3 = (const float*)d_in[0];
    const float* t0p4 = (const float*)d_in[1];
    const float* t0p5 = (const float*)d_in[2];
    const float* t1p3 = (const float*)d_in[3];
    const float* t1p4 = (const float*)d_in[4];
    const float* t1p5 = (const float*)d_in[5];
    const float* t2p3 = (const float*)d_in[6];
    const float* t2p4 = (const float*)d_in[7];
    const float* t2p5 = (const float*)d_in[8];
    const float* sp3  = (const float*)d_in[9];
    const float* sp4  = (const float*)d_in[10];
    const float* sp5  = (const float*)d_in[11];
    const float* f3w1 = (const float*)d_in[12];
    const float* f3b1 = (const float*)d_in[13];
    const float* f3w2 = (const float*)d_in[14];
    const float* f3b2 = (const float*)d_in[15];
    const float* f4w1 = (const float*)d_in[16];
    const float* f4b1 = (const float*)d_in[17];
    const float* f4w2 = (const float*)d_in[18];
    const float* f4b2 = (const float*)d_in[19];
    const float* f5w1 = (const float*)d_in[20];
    const float* f5b1 = (const float*)d_in[21];
    const float* f5w2 = (const float*)d_in[22];
    const float* f5b2 = (const float*)d_in[23];

    float* ws = (float*)d_ws;
    short* abf = (short*)(ws + WS_ABF);
    short* ubuf = (short*)ws;

    prep_kernel<<<11520, 256, 0, stream>>>(t0p3, t1p3, t2p3, t0p4, t1p4, t2p4,
                                           t0p5, t1p5, t2p5,
                                           ws + WS_POOL3, ws + WS_POOL4, ws + WS_MEANS);
    weights_kernel<<<48, 256, 0, stream>>>(ws + WS_MEANS,
                                           f3w1, f3b1, f3w2, f3b2,
                                           f4w1, f4b1, f4w2, f4b2,
                                           f5w1, f5b1, f5w2, f5b2, ws + WS_AW);
    fuse_kernel<<<3840, 256, 0, stream>>>(ws + WS_POOL3, ws + WS_POOL3 + PLSZ, ws + WS_POOL3 + 2 * PLSZ,
                                          ws + WS_POOL4, ws + WS_POOL4 + PLSZ, ws + WS_POOL4 + 2 * PLSZ,
                                          t0p5, t1p5, t2p5,
                                          ws + WS_AW, ws + WS_TF, ws + WS_PART);
    atrans_kernel<<<48, 256, 0, stream>>>(ws + WS_TF, ws + WS_PART, abf);
    gemm_kernel<<<672, 256, 0, stream>>>(sp3, sp4, sp5, abf, ubuf);
    combine_kernel<<<248, 256, 0, stream>>>(ubuf, (float*)d_out);
}

// Round 12
// 87.400 us; speedup vs baseline: 1.3179x; 1.3179x over previous
//
#include <hip/hip_runtime.h>
#include <math.h>

#define BATCH 16
#define CH 320

typedef __attribute__((ext_vector_type(8))) short bf16x8;
typedef __attribute__((ext_vector_type(4))) float f32x4;

union FragU { bf16x8 f; unsigned long long u[2]; };

// ---------------- workspace layout (floats) ----------------
static constexpr size_t PLSZ     = (size_t)BATCH * CH * 64;      // 327680
static constexpr size_t WS_POOL3 = 0;                            // 3*PLSZ (U overlaps later)
static constexpr size_t WS_POOL4 = 3 * PLSZ;
static constexpr size_t WS_TF    = 6 * PLSZ;
static constexpr size_t WS_MEANS = 9 * PLSZ;                     // 2949120
static constexpr size_t WS_AW    = WS_MEANS + 9 * BATCH * CH;    // +46080
static constexpr size_t WS_PART  = WS_AW + 144;
static constexpr size_t WS_ABF   = WS_PART + 3 * BATCH * 80 * 64; // bf16 A, 983040 shorts
// V buffers (bf16 shorts) overlap POOL3/POOL4/TF (dead by GEMM time). Layout [b][x][64p].
static constexpr size_t UB3 = 0;
static constexpr size_t UB4 = (size_t)BATCH * 4096 * 64;         // 4194304
static constexpr size_t UB5 = UB4 + (size_t)BATCH * 1024 * 64;   // 5242880

__device__ __forceinline__ float bf2f(unsigned short u) {
    union { unsigned int i; float f; } x; x.i = ((unsigned int)u) << 16; return x.f;
}
__device__ __forceinline__ unsigned short f2bf(float f) {
    union { float f; unsigned int i; } x; x.f = f;
    return (unsigned short)((x.i + 0x7FFFu + ((x.i >> 16) & 1u)) >> 16);
}
__device__ __forceinline__ unsigned cvtpk(float lo, float hi) {
    unsigned r;
    asm("v_cvt_pk_bf16_f32 %0, %1, %2" : "=v"(r) : "v"(lo), "v"(hi));
    return r;
}

// ---------------- 1) fused pool(p3)+pool(p4)+mean(p5) ----------------
template <int HW, int KK>
__device__ __forceinline__ void pool_body(int idx, const float* __restrict__ a0,
                                          const float* __restrict__ a1, const float* __restrict__ a2,
                                          float* __restrict__ dst, float* __restrict__ means, int lane) {
    constexpr int NPL = BATCH * CH * 64;
    int tmpl = idx / NPL;
    int r = idx % NPL;
    const float* src = (tmpl == 0) ? a0 : ((tmpl == 1) ? a1 : a2);
    int bc = r >> 6;
    int pos = r & 63;
    int oh = pos >> 3, ow = pos & 7;
    const float* base = src + (size_t)bc * HW * HW;
    float s = 0.0f;
    if constexpr (KK == 4) {
#pragma unroll
        for (int i = 0; i < 4; ++i) {
            float4 v = *(const float4*)(base + (oh * 4 + i) * HW + ow * 4);
            s += v.x + v.y + v.z + v.w;
        }
    } else {
#pragma unroll
        for (int i = 0; i < 2; ++i) {
            float2 v = *(const float2*)(base + (oh * 2 + i) * HW + ow * 2);
            s += v.x + v.y;
        }
    }
    s *= (1.0f / (KK * KK));
    dst[idx] = s;
    float m = s;
#pragma unroll
    for (int o = 32; o; o >>= 1) m += __shfl_xor(m, o);
    if (lane == 0) means[tmpl * (BATCH * CH) + bc] = m * (1.0f / 64.0f);
}

__global__ __launch_bounds__(256) void prep_kernel(
    const float* __restrict__ t0p3, const float* __restrict__ t1p3, const float* __restrict__ t2p3,
    const float* __restrict__ t0p4, const float* __restrict__ t1p4, const float* __restrict__ t2p4,
    const float* __restrict__ t0p5, const float* __restrict__ t1p5, const float* __restrict__ t2p5,
    float* __restrict__ pool3, float* __restrict__ pool4, float* __restrict__ means) {
    int bid = blockIdx.x, t = threadIdx.x, lane = t & 63;
    if (bid < 3840) {
        pool_body<32, 4>(bid * 256 + t, t0p3, t1p3, t2p3, pool3, means, lane);
    } else if (bid < 7680) {
        pool_body<16, 2>((bid - 3840) * 256 + t, t0p4, t1p4, t2p4, pool4, means + 3 * BATCH * CH, lane);
    } else {
        int w = ((bid - 7680) * 256 + t) >> 6;
        constexpr int NR = BATCH * CH;
        int tmpl = w / NR, rem = w % NR;
        const float* src = (tmpl == 0) ? t0p5 : ((tmpl == 1) ? t1p5 : t2p5);
        float v = src[(size_t)rem * 64 + lane];
#pragma unroll
        for (int o = 32; o; o >>= 1) v += __shfl_xor(v, o);
        if (lane == 0) means[6 * BATCH * CH + w] = v * (1.0f / 64.0f);
    }
}

// ---------------- 2) fusion weights ----------------
__global__ __launch_bounds__(256) void weights_kernel(const float* __restrict__ means,
        const float* w13, const float* b13, const float* w23, const float* b23,
        const float* w14, const float* b14, const float* w24, const float* b24,
        const float* w15, const float* b15, const float* w25, const float* b25,
        float* __restrict__ a_out) {
    __shared__ float m[3 * CH];
    __shared__ float hv[240];
    __shared__ float sc[3];
    int lvl = blockIdx.x / BATCH;
    int b = blockIdx.x % BATCH;
    int t = threadIdx.x;
    const float* w1 = (lvl == 0) ? w13 : ((lvl == 1) ? w14 : w15);
    const float* b1 = (lvl == 0) ? b13 : ((lvl == 1) ? b14 : b15);
    const float* w2 = (lvl == 0) ? w23 : ((lvl == 1) ? w24 : w25);
    const float* b2 = (lvl == 0) ? b23 : ((lvl == 1) ? b24 : b25);
    const float* mb = means + lvl * (3 * BATCH * CH);
    for (int j = t; j < 3 * CH; j += 256) {
        int i = j / CH, c = j % CH;
        m[j] = mb[i * (BATCH * CH) + b * CH + c];
    }
    __syncthreads();
    if (t < 240) {
        int i = t / 80, jj = t % 80;
        float acc = b1[jj];
#pragma unroll 4
        for (int c = 0; c < CH; ++c) acc = fmaf(m[i * CH + c], w1[c * 80 + jj], acc);
        hv[t] = fmaxf(acc, 0.0f) * w2[jj];
    }
    __syncthreads();
    if (t < 3) {
        float s = b2[0];
#pragma unroll 8
        for (int jj = 0; jj < 80; ++jj) s += hv[t * 80 + jj];
        sc[t] = s;
    }
    __syncthreads();
    if (t == 0) {
        float mx = fmaxf(sc[0], fmaxf(sc[1], sc[2]));
        float e0 = expf(sc[0] - mx), e1 = expf(sc[1] - mx), e2 = expf(sc[2] - mx);
        float inv = 1.0f / (e0 + e1 + e2);
        float* ao = a_out + lvl * 48 + b * 3;
        ao[0] = e0 * inv; ao[1] = e1 * inv; ao[2] = e2 * inv;
    }
}

// ---------------- 3a) fuse templates + partial sum of squares ----------------
__global__ __launch_bounds__(256) void fuse_kernel(
        const float* __restrict__ p30, const float* __restrict__ p31, const float* __restrict__ p32,
        const float* __restrict__ p40, const float* __restrict__ p41, const float* __restrict__ p42,
        const float* __restrict__ p50, const float* __restrict__ p51, const float* __restrict__ p52,
        const float* __restrict__ aw, float* __restrict__ tf, float* __restrict__ partial) {
    __shared__ float red[256];
    int lvl = blockIdx.x / 1280;
    int r = blockIdx.x % 1280;
    int t = threadIdx.x;
    const float* p0 = (lvl == 0) ? p30 : ((lvl == 1) ? p40 : p50);
    const float* p1 = (lvl == 0) ? p31 : ((lvl == 1) ? p41 : p51);
    const float* p2 = (lvl == 0) ? p32 : ((lvl == 1) ? p42 : p52);
    int idx = r * 256 + t;
    int b = r / 80;
    int j = r % 80;
    const float* ab = aw + lvl * 48 + b * 3;
    float a0 = ab[0], a1 = ab[1], a2 = ab[2];
    float v = a0 * p0[idx] + a1 * p1[idx] + a2 * p2[idx];
    tf[(size_t)lvl * PLSZ + idx] = v;
    red[t] = v * v;
    __syncthreads();
    if (t < 64) {
        float s = red[t] + red[t + 64] + red[t + 128] + red[t + 192];
        partial[((size_t)(lvl * BATCH + b) * 80 + j) * 64 + t] = s;
    }
}

// ---------------- 3b) finalize sinv + transpose + scale -> bf16 A [lvl][b][p][c] ----------------
// Split across c-chunks: grid = 48 (lvl,b) x 5 (64-c chunk) = 240 blocks (was 48 -> CU-starved).
__global__ __launch_bounds__(256) void atrans_kernel(const float* __restrict__ tf,
        const float* __restrict__ part, short* __restrict__ abf) {
    __shared__ float lds[64 * 68];
    __shared__ float red2[4 * 64];
    __shared__ float sv[64];
    int lvlb = blockIdx.x / 5;
    int c0 = (blockIdx.x % 5) * 64;
    int lvl = lvlb >> 4;
    int b = lvlb & 15;
    int t = threadIdx.x;
    {   // sv recomputed per block (reads 20KB of partials -- cheap, removes cross-block dep)
        const float* p = part + ((size_t)(lvl * BATCH + b) * 80) * 64 + (t & 63);
        int jg = t >> 6;
        float s = 0.0f;
        for (int j = jg * 20; j < jg * 20 + 20; ++j) s += p[j * 64];
        red2[jg * 64 + (t & 63)] = s;
    }
    __syncthreads();
    if (t < 64) {
        float s = red2[t] + red2[64 + t] + red2[128 + t] + red2[192 + t];
        sv[t] = 1.0f / fmaxf(sqrtf(s), 1e-12f);
    }
    __syncthreads();
    const float* tb = tf + (size_t)lvl * PLSZ + (size_t)b * (CH * 64);
    short* ab = abf + ((size_t)(lvl * BATCH + b) * 64) * 320;
#pragma unroll
    for (int i = 0; i < 4; ++i) {
        int c = (t >> 4) + 16 * i;
        int p4 = (t & 15) * 4;
        *(float4*)(lds + c * 68 + p4) = *(const float4*)(tb + (size_t)(c0 + c) * 64 + p4);
    }
    __syncthreads();
    int p = t >> 2;
    int cs = (t & 3) * 16;
    float s_p = sv[p];
    bf16x8 o0, o1;
#pragma unroll
    for (int u = 0; u < 8; ++u) o0[u] = (short)f2bf(lds[(cs + u) * 68 + p] * s_p);
#pragma unroll
    for (int u = 0; u < 8; ++u) o1[u] = (short)f2bf(lds[(cs + 8 + u) * 68 + p] * s_p);
    *(bf16x8*)(ab + (size_t)p * 320 + c0 + cs) = o0;
    *(bf16x8*)(ab + (size_t)p * 320 + c0 + cs + 8) = o1;
}

// ---------------- 4) swapped-operand MFMA GEMM (R10-benched structure, placeholder removed) ----------------
// V[b][x][p] = inv[x] * sum_c T[p][c] * S[b][c][x]
// Block 256 thr / 4 waves, x-tile 128. Wave w: x-slice [w*32,w*32+32) (2 m-tiles) x ALL 64 p
// (4 n-frags) -> acc[2][4], 8 MFMA/step, full 128B V-line writes. 512B read grain.
// T double-buffered in regs (one step ahead: exposing T's L2 latency per-step cost +18us, R11).
template <int N>
__device__ __forceinline__ void gemm_body(const float* __restrict__ S, const short* __restrict__ T,
                                          short* __restrict__ V, int bid, unsigned short* St) {
    constexpr int XB = N / 128;
    int b = bid / XB;
    int x0b = (bid % XB) * 128;
    int t = threadIdx.x;
    int w = t >> 6, l = t & 63, g = l >> 4, ln = l & 15;
    int fidx = t & 31;                 // x float4-chunk (x = fidx*4, in [0,128))
    int rg = t >> 5;                   // 0..7 row group (c ≡ rg mod 8)

    const float* Sp = S + (size_t)b * CH * N + x0b + fidx * 4;
    const short* Tb = T + (size_t)b * 64 * 320;

    f32x4 acc[2][4];
#pragma unroll
    for (int i = 0; i < 2; ++i)
#pragma unroll
        for (int j = 0; j < 4; ++j) acc[i][j] = (f32x4){0.f, 0.f, 0.f, 0.f};
    float ssq[4] = {0.f, 0.f, 0.f, 0.f};

    // staging LDS offset (shorts), validated subtile map per 64-x half:
    int ebase = (fidx >> 4) * 2048 + (((fidx >> 2) & 3) * 8 + (rg >> 2)) * 64 + (rg & 3) * 16 + (fidx & 3) * 4;
    // tr-read lane base (bytes): half (w>>1), 16x-group (w&1)*2+mt (mt at +1024), validated map
    unsigned trbase = (unsigned)(size_t)St + (unsigned)((w >> 1) * 4096 + (w & 1) * 2048 + g * 256 + ln * 8);

#define LOADR(DST, S_) { \
    _Pragma("unroll") \
    for (int i = 0; i < 4; ++i) \
        DST[i] = *(const float4*)(Sp + (size_t)(32 * (S_) + rg + 8 * i) * N); }

#define LOADT(DST, S_) { \
    _Pragma("unroll") \
    for (int j = 0; j < 4; ++j) \
        DST[j] = *(const bf16x8*)(Tb + (size_t)(j * 16 + ln) * 320 + 32 * (S_) + 8 * g); }

#define STAGE(SRC, BUF) { \
    _Pragma("unroll") \
    for (int i = 0; i < 4; ++i) { \
        float4 v = SRC[i]; \
        ssq[0] = fmaf(v.x, v.x, ssq[0]); ssq[1] = fmaf(v.y, v.y, ssq[1]); \
        ssq[2] = fmaf(v.z, v.z, ssq[2]); ssq[3] = fmaf(v.w, v.w, ssq[3]); \
        *(uint2*)(St + (BUF) * 4096 + ebase + i * 128) = (uint2){cvtpk(v.x, v.y), cvtpk(v.z, v.w)}; \
    } }

#define TRRD2(FR, OFF) \
    asm volatile("ds_read_b64_tr_b16 %0, %2 offset:%c3\n\tds_read_b64_tr_b16 %1, %2 offset:%c4" \
                 : "=v"((FR).u[0]), "=v"((FR).u[1]) : "v"(trbase), "i"(OFF), "i"((OFF) + 128));

    // ---- prologue: load + stage step 0, load T0 ----
    float4 pv[4];
    bf16x8 tcur[4];
    LOADR(pv, 0)
    LOADT(tcur, 0)
    STAGE(pv, 0)
    __syncthreads();

#pragma unroll
    for (int s = 0; s < 10; ++s) {
        const int cur = s & 1;
        float4 nv[4];
        bf16x8 tnx[4];
        if (s < 9) {                 // issue next-step loads (fly under MFMAs)
            LOADR(nv, s + 1)
            LOADT(tnx, s + 1)
        }
        // A-fragments from buf[cur] via hardware-transpose reads (compile-time offsets)
        FragU fa0, fa1;
        if (cur == 0) { TRRD2(fa0, 0)    TRRD2(fa1, 1024) }
        else          { TRRD2(fa0, 8192) TRRD2(fa1, 8192 + 1024) }
        asm volatile("s_waitcnt lgkmcnt(0)" ::: "memory");
        __builtin_amdgcn_sched_barrier(0);
        __builtin_amdgcn_s_setprio(1);
        acc[0][0] = __builtin_amdgcn_mfma_f32_16x16x32_bf16(fa0.f, tcur[0], acc[0][0], 0, 0, 0);
        acc[0][1] = __builtin_amdgcn_mfma_f32_16x16x32_bf16(fa0.f, tcur[1], acc[0][1], 0, 0, 0);
        acc[0][2] = __builtin_amdgcn_mfma_f32_16x16x32_bf16(fa0.f, tcur[2], acc[0][2], 0, 0, 0);
        acc[0][3] = __builtin_amdgcn_mfma_f32_16x16x32_bf16(fa0.f, tcur[3], acc[0][3], 0, 0, 0);
        acc[1][0] = __builtin_amdgcn_mfma_f32_16x16x32_bf16(fa1.f, tcur[0], acc[1][0], 0, 0, 0);
        acc[1][1] = __builtin_amdgcn_mfma_f32_16x16x32_bf16(fa1.f, tcur[1], acc[1][1], 0, 0, 0);
        acc[1][2] = __builtin_amdgcn_mfma_f32_16x16x32_bf16(fa1.f, tcur[2], acc[1][2], 0, 0, 0);
        acc[1][3] = __builtin_amdgcn_mfma_f32_16x16x32_bf16(fa1.f, tcur[3], acc[1][3], 0, 0, 0);
        __builtin_amdgcn_s_setprio(0);
        if (s < 9) {
            STAGE(nv, cur ^ 1)       // counted vmcnt wait inserted at first use of nv
#pragma unroll
            for (int j = 0; j < 4; ++j) tcur[j] = tnx[j];
        }
        __syncthreads();
    }
#undef TRRD2
#undef STAGE
#undef LOADT
#undef LOADR

    // ---- per-x inverse search norms (alias dead LDS as floats) ----
    float* Sf = (float*)St;
    *(f32x4*)(Sf + rg * 128 + fidx * 4) = (f32x4){ssq[0], ssq[1], ssq[2], ssq[3]};
    __syncthreads();
    float invv = 0.0f;
    if (t < 128) {
        float s = 0.0f;
#pragma unroll
        for (int i = 0; i < 8; ++i) s += Sf[i * 128 + t];
        invv = 1.0f / fmaxf(sqrtf(s), 1e-12f);
    }
    __syncthreads();
    if (t < 128) Sf[1024 + t] = invv;
    __syncthreads();

    // ---- V write: wave w covers x = w*32 + mt*16 + 4g + r, ALL p (full 128B lines) ----
#pragma unroll
    for (int mt = 0; mt < 2; ++mt) {
#pragma unroll
        for (int r = 0; r < 4; ++r) {
            int xl = w * 32 + mt * 16 + 4 * g + r;
            float iv = Sf[1024 + xl];
            short* vp = V + ((size_t)b * N + x0b + xl) * 64 + ln;
            vp[0]  = (short)f2bf(acc[mt][0][r] * iv);
            vp[16] = (short)f2bf(acc[mt][1][r] * iv);
            vp[32] = (short)f2bf(acc[mt][2][r] * iv);
            vp[48] = (short)f2bf(acc[mt][3][r] * iv);
        }
    }
}

__global__ __launch_bounds__(256, 2) void gemm_kernel(const float* __restrict__ sp3,
        const float* __restrict__ sp4, const float* __restrict__ sp5,
        const short* __restrict__ abf, short* __restrict__ u) {
    __shared__ unsigned short St[2 * 4096];   // 16KB double buffer (epilogue aliases it)
    int bid = blockIdx.x;
    if (bid < 512)      gemm_body<4096>(sp3, abf,          u + UB3, bid,       St);
    else if (bid < 640) gemm_body<1024>(sp4, abf + 327680, u + UB4, bid - 512, St);
    else                gemm_body<256>(sp5, abf + 655360,  u + UB5, bid - 640, St);
}

// ---------------- 5) combine: out[oh][ow] = sum_{kh,kw} V[(oh+kh)*H+ow+kw][kh*8+kw] ----------------
__global__ __launch_bounds__(256) void combine_kernel(const short* __restrict__ U,
                                                      float* __restrict__ out) {
    int tid = blockIdx.x * 256 + threadIdx.x;
    if (tid < 51984) {
        int b = tid / 3249, r = tid % 3249;
        int oh = r / 57, ow = r % 57;
        const short* u = U + UB3 + ((size_t)b * 4096 + oh * 64 + ow) * 64;
        float s = 0.0f;
#pragma unroll
        for (int kh = 0; kh < 8; ++kh)
#pragma unroll
            for (int kw = 0; kw < 8; ++kw)
                s += bf2f((unsigned short)u[(kh * 64 + kw) * 64 + kh * 8 + kw]);
        out[tid] = s;
    } else if (tid < 61984) {
        int x = tid - 51984;
        int b = x / 625, r = x % 625;
        int oh = r / 25, ow = r % 25;
        const short* u = U + UB4 + ((size_t)b * 1024 + oh * 32 + ow) * 64;
        float s = 0.0f;
#pragma unroll
        for (int kh = 0; kh < 8; ++kh)
#pragma unroll
            for (int kw = 0; kw < 8; ++kw)
                s += bf2f((unsigned short)u[(kh * 32 + kw) * 64 + kh * 8 + kw]);
        out[tid] = s;
    } else if (tid < 63280) {
        int x = tid - 61984;
        int b = x / 81, r = x % 81;
        int oh = r / 9, ow = r % 9;
        const short* u = U + UB5 + ((size_t)b * 256 + oh * 16 + ow) * 64;
        float s = 0.0f;
#pragma unroll
        for (int kh = 0; kh < 8; ++kh)
#pragma unroll
            for (int kw = 0; kw < 8; ++kw)
                s += bf2f((unsigned short)u[(kh * 16 + kw) * 64 + kh * 8 + kw]);
        out[tid] = s;
    }
}

extern "C" void kernel_launch(void* const* d_in, const int* in_sizes, int n_in,
                              void* d_out, int out_size, void* d_ws, size_t ws_size,
                              hipStream_t stream) {
    const float* t0p3 = (const float*)d_in[0];
    const float* t0p4 = (const float*)d_in[1];
    const float* t0p5 = (const float*)d_in[2];
    const float* t1p3 = (const float*)d_in[3];
    const float* t1p4 = (const float*)d_in[4];
    const float* t1p5 = (const float*)d_in[5];
    const float* t2p3 = (const float*)d_in[6];
    const float* t2p4 = (const float*)d_in[7];
    const float* t2p5 = (const float*)d_in[8];
    const float* sp3  = (const float*)d_in[9];
    const float* sp4  = (const float*)d_in[10];
    const float* sp5  = (const float*)d_in[11];
    const float* f3w1 = (const float*)d_in[12];
    const float* f3b1 = (const float*)d_in[13];
    const float* f3w2 = (const float*)d_in[14];
    const float* f3b2 = (const float*)d_in[15];
    const float* f4w1 = (const float*)d_in[16];
    const float* f4b1 = (const float*)d_in[17];
    const float* f4w2 = (const float*)d_in[18];
    const float* f4b2 = (const float*)d_in[19];
    const float* f5w1 = (const float*)d_in[20];
    const float* f5b1 = (const float*)d_in[21];
    const float* f5w2 = (const float*)d_in[22];
    const float* f5b2 = (const float*)d_in[23];

    float* ws = (float*)d_ws;
    short* abf = (short*)(ws + WS_ABF);
    short* ubuf = (short*)ws;

    prep_kernel<<<11520, 256, 0, stream>>>(t0p3, t1p3, t2p3, t0p4, t1p4, t2p4,
                                           t0p5, t1p5, t2p5,
                                           ws + WS_POOL3, ws + WS_POOL4, ws + WS_MEANS);
    weights_kernel<<<48, 256, 0, stream>>>(ws + WS_MEANS,
                                           f3w1, f3b1, f3w2, f3b2,
                                           f4w1, f4b1, f4w2, f4b2,
                                           f5w1, f5b1, f5w2, f5b2, ws + WS_AW);
    fuse_kernel<<<3840, 256, 0, stream>>>(ws + WS_POOL3, ws + WS_POOL3 + PLSZ, ws + WS_POOL3 + 2 * PLSZ,
                                          ws + WS_POOL4, ws + WS_POOL4 + PLSZ, ws + WS_POOL4 + 2 * PLSZ,
                                          t0p5, t1p5, t2p5,
                                          ws + WS_AW, ws + WS_TF, ws + WS_PART);
    atrans_kernel<<<240, 256, 0, stream>>>(ws + WS_TF, ws + WS_PART, abf);
    gemm_kernel<<<672, 256, 0, stream>>>(sp3, sp4, sp5, abf, ubuf);
    combine_kernel<<<248, 256, 0, stream>>>(ubuf, (float*)d_out);
}

// Round 13
// 86.581 us; speedup vs baseline: 1.3304x; 1.0095x over previous
//
#include <hip/hip_runtime.h>
#include <math.h>

#define BATCH 16
#define CH 320

typedef __attribute__((ext_vector_type(8))) short bf16x8;
typedef __attribute__((ext_vector_type(4))) float f32x4;

union FragU { bf16x8 f; unsigned long long u[2]; };

// ---------------- workspace layout (floats) ----------------
static constexpr size_t PLSZ     = (size_t)BATCH * CH * 64;      // 327680
static constexpr size_t WS_POOL3 = 0;                            // 3*PLSZ (U overlaps later)
static constexpr size_t WS_POOL4 = 3 * PLSZ;
static constexpr size_t WS_TF    = 6 * PLSZ;
static constexpr size_t WS_MEANS = 9 * PLSZ;                     // 2949120
static constexpr size_t WS_AW    = WS_MEANS + 9 * BATCH * CH;    // +46080
static constexpr size_t WS_PART  = WS_AW + 144;
static constexpr size_t WS_ABF   = WS_PART + 3 * BATCH * 80 * 64; // bf16 A, 983040 shorts
// V buffers (bf16 shorts) overlap POOL3/POOL4/TF (dead by GEMM time). Layout [b][x][64p].
static constexpr size_t UB3 = 0;
static constexpr size_t UB4 = (size_t)BATCH * 4096 * 64;         // 4194304
static constexpr size_t UB5 = UB4 + (size_t)BATCH * 1024 * 64;   // 5242880

__device__ __forceinline__ float bf2f(unsigned short u) {
    union { unsigned int i; float f; } x; x.i = ((unsigned int)u) << 16; return x.f;
}
__device__ __forceinline__ unsigned short f2bf(float f) {
    union { float f; unsigned int i; } x; x.f = f;
    return (unsigned short)((x.i + 0x7FFFu + ((x.i >> 16) & 1u)) >> 16);
}
__device__ __forceinline__ unsigned cvtpk(float lo, float hi) {
    unsigned r;
    asm("v_cvt_pk_bf16_f32 %0, %1, %2" : "=v"(r) : "v"(lo), "v"(hi));
    return r;
}

// ---------------- 1) fused pool(p3)+pool(p4)+mean(p5) ----------------
template <int HW, int KK>
__device__ __forceinline__ void pool_body(int idx, const float* __restrict__ a0,
                                          const float* __restrict__ a1, const float* __restrict__ a2,
                                          float* __restrict__ dst, float* __restrict__ means, int lane) {
    constexpr int NPL = BATCH * CH * 64;
    int tmpl = idx / NPL;
    int r = idx % NPL;
    const float* src = (tmpl == 0) ? a0 : ((tmpl == 1) ? a1 : a2);
    int bc = r >> 6;
    int pos = r & 63;
    int oh = pos >> 3, ow = pos & 7;
    const float* base = src + (size_t)bc * HW * HW;
    float s = 0.0f;
    if constexpr (KK == 4) {
#pragma unroll
        for (int i = 0; i < 4; ++i) {
            float4 v = *(const float4*)(base + (oh * 4 + i) * HW + ow * 4);
            s += v.x + v.y + v.z + v.w;
        }
    } else {
#pragma unroll
        for (int i = 0; i < 2; ++i) {
            float2 v = *(const float2*)(base + (oh * 2 + i) * HW + ow * 2);
            s += v.x + v.y;
        }
    }
    s *= (1.0f / (KK * KK));
    dst[idx] = s;
    float m = s;
#pragma unroll
    for (int o = 32; o; o >>= 1) m += __shfl_xor(m, o);
    if (lane == 0) means[tmpl * (BATCH * CH) + bc] = m * (1.0f / 64.0f);
}

__global__ __launch_bounds__(256) void prep_kernel(
    const float* __restrict__ t0p3, const float* __restrict__ t1p3, const float* __restrict__ t2p3,
    const float* __restrict__ t0p4, const float* __restrict__ t1p4, const float* __restrict__ t2p4,
    const float* __restrict__ t0p5, const float* __restrict__ t1p5, const float* __restrict__ t2p5,
    float* __restrict__ pool3, float* __restrict__ pool4, float* __restrict__ means) {
    int bid = blockIdx.x, t = threadIdx.x, lane = t & 63;
    if (bid < 3840) {
        pool_body<32, 4>(bid * 256 + t, t0p3, t1p3, t2p3, pool3, means, lane);
    } else if (bid < 7680) {
        pool_body<16, 2>((bid - 3840) * 256 + t, t0p4, t1p4, t2p4, pool4, means + 3 * BATCH * CH, lane);
    } else {
        int w = ((bid - 7680) * 256 + t) >> 6;
        constexpr int NR = BATCH * CH;
        int tmpl = w / NR, rem = w % NR;
        const float* src = (tmpl == 0) ? t0p5 : ((tmpl == 1) ? t1p5 : t2p5);
        float v = src[(size_t)rem * 64 + lane];
#pragma unroll
        for (int o = 32; o; o >>= 1) v += __shfl_xor(v, o);
        if (lane == 0) means[6 * BATCH * CH + w] = v * (1.0f / 64.0f);
    }
}

// ---------------- 2) fusion weights ----------------
__global__ __launch_bounds__(256) void weights_kernel(const float* __restrict__ means,
        const float* w13, const float* b13, const float* w23, const float* b23,
        const float* w14, const float* b14, const float* w24, const float* b24,
        const float* w15, const float* b15, const float* w25, const float* b25,
        float* __restrict__ a_out) {
    __shared__ float m[3 * CH];
    __shared__ float hv[240];
    __shared__ float sc[3];
    int lvl = blockIdx.x / BATCH;
    int b = blockIdx.x % BATCH;
    int t = threadIdx.x;
    const float* w1 = (lvl == 0) ? w13 : ((lvl == 1) ? w14 : w15);
    const float* b1 = (lvl == 0) ? b13 : ((lvl == 1) ? b14 : b15);
    const float* w2 = (lvl == 0) ? w23 : ((lvl == 1) ? w24 : w25);
    const float* b2 = (lvl == 0) ? b23 : ((lvl == 1) ? b24 : b25);
    const float* mb = means + lvl * (3 * BATCH * CH);
    for (int j = t; j < 3 * CH; j += 256) {
        int i = j / CH, c = j % CH;
        m[j] = mb[i * (BATCH * CH) + b * CH + c];
    }
    __syncthreads();
    if (t < 240) {
        int i = t / 80, jj = t % 80;
        float acc = b1[jj];
#pragma unroll 4
        for (int c = 0; c < CH; ++c) acc = fmaf(m[i * CH + c], w1[c * 80 + jj], acc);
        hv[t] = fmaxf(acc, 0.0f) * w2[jj];
    }
    __syncthreads();
    if (t < 3) {
        float s = b2[0];
#pragma unroll 8
        for (int jj = 0; jj < 80; ++jj) s += hv[t * 80 + jj];
        sc[t] = s;
    }
    __syncthreads();
    if (t == 0) {
        float mx = fmaxf(sc[0], fmaxf(sc[1], sc[2]));
        float e0 = expf(sc[0] - mx), e1 = expf(sc[1] - mx), e2 = expf(sc[2] - mx);
        float inv = 1.0f / (e0 + e1 + e2);
        float* ao = a_out + lvl * 48 + b * 3;
        ao[0] = e0 * inv; ao[1] = e1 * inv; ao[2] = e2 * inv;
    }
}

// ---------------- 3a) fuse templates + partial sum of squares ----------------
__global__ __launch_bounds__(256) void fuse_kernel(
        const float* __restrict__ p30, const float* __restrict__ p31, const float* __restrict__ p32,
        const float* __restrict__ p40, const float* __restrict__ p41, const float* __restrict__ p42,
        const float* __restrict__ p50, const float* __restrict__ p51, const float* __restrict__ p52,
        const float* __restrict__ aw, float* __restrict__ tf, float* __restrict__ partial) {
    __shared__ float red[256];
    int lvl = blockIdx.x / 1280;
    int r = blockIdx.x % 1280;
    int t = threadIdx.x;
    const float* p0 = (lvl == 0) ? p30 : ((lvl == 1) ? p40 : p50);
    const float* p1 = (lvl == 0) ? p31 : ((lvl == 1) ? p41 : p51);
    const float* p2 = (lvl == 0) ? p32 : ((lvl == 1) ? p42 : p52);
    int idx = r * 256 + t;
    int b = r / 80;
    int j = r % 80;
    const float* ab = aw + lvl * 48 + b * 3;
    float a0 = ab[0], a1 = ab[1], a2 = ab[2];
    float v = a0 * p0[idx] + a1 * p1[idx] + a2 * p2[idx];
    tf[(size_t)lvl * PLSZ + idx] = v;
    red[t] = v * v;
    __syncthreads();
    if (t < 64) {
        float s = red[t] + red[t + 64] + red[t + 128] + red[t + 192];
        partial[((size_t)(lvl * BATCH + b) * 80 + j) * 64 + t] = s;
    }
}

// ---------------- 3b) finalize sinv + transpose + scale -> bf16 A [lvl][b][p][c] ----------------
// Split across c-chunks: grid = 48 (lvl,b) x 5 (64-c chunk) = 240 blocks.
__global__ __launch_bounds__(256) void atrans_kernel(const float* __restrict__ tf,
        const float* __restrict__ part, short* __restrict__ abf) {
    __shared__ float lds[64 * 68];
    __shared__ float red2[4 * 64];
    __shared__ float sv[64];
    int lvlb = blockIdx.x / 5;
    int c0 = (blockIdx.x % 5) * 64;
    int lvl = lvlb >> 4;
    int b = lvlb & 15;
    int t = threadIdx.x;
    {   // sv recomputed per block (reads 20KB of partials -- cheap, removes cross-block dep)
        const float* p = part + ((size_t)(lvl * BATCH + b) * 80) * 64 + (t & 63);
        int jg = t >> 6;
        float s = 0.0f;
        for (int j = jg * 20; j < jg * 20 + 20; ++j) s += p[j * 64];
        red2[jg * 64 + (t & 63)] = s;
    }
    __syncthreads();
    if (t < 64) {
        float s = red2[t] + red2[64 + t] + red2[128 + t] + red2[192 + t];
        sv[t] = 1.0f / fmaxf(sqrtf(s), 1e-12f);
    }
    __syncthreads();
    const float* tb = tf + (size_t)lvl * PLSZ + (size_t)b * (CH * 64);
    short* ab = abf + ((size_t)(lvl * BATCH + b) * 64) * 320;
#pragma unroll
    for (int i = 0; i < 4; ++i) {
        int c = (t >> 4) + 16 * i;
        int p4 = (t & 15) * 4;
        *(float4*)(lds + c * 68 + p4) = *(const float4*)(tb + (size_t)(c0 + c) * 64 + p4);
    }
    __syncthreads();
    int p = t >> 2;
    int cs = (t & 3) * 16;
    float s_p = sv[p];
    bf16x8 o0, o1;
#pragma unroll
    for (int u = 0; u < 8; ++u) o0[u] = (short)f2bf(lds[(cs + u) * 68 + p] * s_p);
#pragma unroll
    for (int u = 0; u < 8; ++u) o1[u] = (short)f2bf(lds[(cs + 8 + u) * 68 + p] * s_p);
    *(bf16x8*)(ab + (size_t)p * 320 + c0 + cs) = o0;
    *(bf16x8*)(ab + (size_t)p * 320 + c0 + cs + 8) = o1;
}

// ---------------- 4) swapped-operand MFMA GEMM (R12 structure + XCD-contiguous remap) ----------------
// V[b][x][p] = inv[x] * sum_c T[p][c] * S[b][c][x]
// Body identical to R12 (benched 49 us). The dispatch->(b,xt) remap gives each XCD two
// complete batches: its concurrently-resident blocks read a CONTIGUOUS ~10.5MB S region
// with fully dense 16KB c-rows (vs 512B-of-16KB sparse per-XCD streams under round-robin).
template <int N>
__device__ __forceinline__ void gemm_body(const float* __restrict__ S, const short* __restrict__ T,
                                          short* __restrict__ V, int bid, unsigned short* St) {
    constexpr int XB = N / 128;
    int b = bid / XB;
    int x0b = (bid % XB) * 128;
    int t = threadIdx.x;
    int w = t >> 6, l = t & 63, g = l >> 4, ln = l & 15;
    int fidx = t & 31;                 // x float4-chunk (x = fidx*4, in [0,128))
    int rg = t >> 5;                   // 0..7 row group (c ≡ rg mod 8)

    const float* Sp = S + (size_t)b * CH * N + x0b + fidx * 4;
    const short* Tb = T + (size_t)b * 64 * 320;

    f32x4 acc[2][4];
#pragma unroll
    for (int i = 0; i < 2; ++i)
#pragma unroll
        for (int j = 0; j < 4; ++j) acc[i][j] = (f32x4){0.f, 0.f, 0.f, 0.f};
    float ssq[4] = {0.f, 0.f, 0.f, 0.f};

    // staging LDS offset (shorts), validated subtile map per 64-x half:
    int ebase = (fidx >> 4) * 2048 + (((fidx >> 2) & 3) * 8 + (rg >> 2)) * 64 + (rg & 3) * 16 + (fidx & 3) * 4;
    // tr-read lane base (bytes): half (w>>1), 16x-group (w&1)*2+mt (mt at +1024), validated map
    unsigned trbase = (unsigned)(size_t)St + (unsigned)((w >> 1) * 4096 + (w & 1) * 2048 + g * 256 + ln * 8);

#define LOADR(DST, S_) { \
    _Pragma("unroll") \
    for (int i = 0; i < 4; ++i) \
        DST[i] = *(const float4*)(Sp + (size_t)(32 * (S_) + rg + 8 * i) * N); }

#define LOADT(DST, S_) { \
    _Pragma("unroll") \
    for (int j = 0; j < 4; ++j) \
        DST[j] = *(const bf16x8*)(Tb + (size_t)(j * 16 + ln) * 320 + 32 * (S_) + 8 * g); }

#define STAGE(SRC, BUF) { \
    _Pragma("unroll") \
    for (int i = 0; i < 4; ++i) { \
        float4 v = SRC[i]; \
        ssq[0] = fmaf(v.x, v.x, ssq[0]); ssq[1] = fmaf(v.y, v.y, ssq[1]); \
        ssq[2] = fmaf(v.z, v.z, ssq[2]); ssq[3] = fmaf(v.w, v.w, ssq[3]); \
        *(uint2*)(St + (BUF) * 4096 + ebase + i * 128) = (uint2){cvtpk(v.x, v.y), cvtpk(v.z, v.w)}; \
    } }

#define TRRD2(FR, OFF) \
    asm volatile("ds_read_b64_tr_b16 %0, %2 offset:%c3\n\tds_read_b64_tr_b16 %1, %2 offset:%c4" \
                 : "=v"((FR).u[0]), "=v"((FR).u[1]) : "v"(trbase), "i"(OFF), "i"((OFF) + 128));

    // ---- prologue: load + stage step 0, load T0 ----
    float4 pv[4];
    bf16x8 tcur[4];
    LOADR(pv, 0)
    LOADT(tcur, 0)
    STAGE(pv, 0)
    __syncthreads();

#pragma unroll
    for (int s = 0; s < 10; ++s) {
        const int cur = s & 1;
        float4 nv[4];
        bf16x8 tnx[4];
        if (s < 9) {                 // issue next-step loads (fly under MFMAs)
            LOADR(nv, s + 1)
            LOADT(tnx, s + 1)
        }
        // A-fragments from buf[cur] via hardware-transpose reads (compile-time offsets)
        FragU fa0, fa1;
        if (cur == 0) { TRRD2(fa0, 0)    TRRD2(fa1, 1024) }
        else          { TRRD2(fa0, 8192) TRRD2(fa1, 8192 + 1024) }
        asm volatile("s_waitcnt lgkmcnt(0)" ::: "memory");
        __builtin_amdgcn_sched_barrier(0);
        __builtin_amdgcn_s_setprio(1);
        acc[0][0] = __builtin_amdgcn_mfma_f32_16x16x32_bf16(fa0.f, tcur[0], acc[0][0], 0, 0, 0);
        acc[0][1] = __builtin_amdgcn_mfma_f32_16x16x32_bf16(fa0.f, tcur[1], acc[0][1], 0, 0, 0);
        acc[0][2] = __builtin_amdgcn_mfma_f32_16x16x32_bf16(fa0.f, tcur[2], acc[0][2], 0, 0, 0);
        acc[0][3] = __builtin_amdgcn_mfma_f32_16x16x32_bf16(fa0.f, tcur[3], acc[0][3], 0, 0, 0);
        acc[1][0] = __builtin_amdgcn_mfma_f32_16x16x32_bf16(fa1.f, tcur[0], acc[1][0], 0, 0, 0);
        acc[1][1] = __builtin_amdgcn_mfma_f32_16x16x32_bf16(fa1.f, tcur[1], acc[1][1], 0, 0, 0);
        acc[1][2] = __builtin_amdgcn_mfma_f32_16x16x32_bf16(fa1.f, tcur[2], acc[1][2], 0, 0, 0);
        acc[1][3] = __builtin_amdgcn_mfma_f32_16x16x32_bf16(fa1.f, tcur[3], acc[1][3], 0, 0, 0);
        __builtin_amdgcn_s_setprio(0);
        if (s < 9) {
            STAGE(nv, cur ^ 1)       // counted vmcnt wait inserted at first use of nv
#pragma unroll
            for (int j = 0; j < 4; ++j) tcur[j] = tnx[j];
        }
        __syncthreads();
    }
#undef TRRD2
#undef STAGE
#undef LOADT
#undef LOADR

    // ---- per-x inverse search norms (alias dead LDS as floats) ----
    float* Sf = (float*)St;
    *(f32x4*)(Sf + rg * 128 + fidx * 4) = (f32x4){ssq[0], ssq[1], ssq[2], ssq[3]};
    __syncthreads();
    float invv = 0.0f;
    if (t < 128) {
        float s = 0.0f;
#pragma unroll
        for (int i = 0; i < 8; ++i) s += Sf[i * 128 + t];
        invv = 1.0f / fmaxf(sqrtf(s), 1e-12f);
    }
    __syncthreads();
    if (t < 128) Sf[1024 + t] = invv;
    __syncthreads();

    // ---- V write: wave w covers x = w*32 + mt*16 + 4g + r, ALL p (full 128B lines) ----
#pragma unroll
    for (int mt = 0; mt < 2; ++mt) {
#pragma unroll
        for (int r = 0; r < 4; ++r) {
            int xl = w * 32 + mt * 16 + 4 * g + r;
            float iv = Sf[1024 + xl];
            short* vp = V + ((size_t)b * N + x0b + xl) * 64 + ln;
            vp[0]  = (short)f2bf(acc[mt][0][r] * iv);
            vp[16] = (short)f2bf(acc[mt][1][r] * iv);
            vp[32] = (short)f2bf(acc[mt][2][r] * iv);
            vp[48] = (short)f2bf(acc[mt][3][r] * iv);
        }
    }
}

__global__ __launch_bounds__(256, 2) void gemm_kernel(const float* __restrict__ sp3,
        const float* __restrict__ sp4, const float* __restrict__ sp5,
        const short* __restrict__ abf, short* __restrict__ u) {
    __shared__ unsigned short St[2 * 4096];   // 16KB double buffer (epilogue aliases it)
    int d = blockIdx.x;
    // XCD-contiguous remap (bijective; dispatch idx % 8 ~ XCD round-robin heuristic):
    // XCD k owns batches {2k, 2k+1} -> its resident blocks read one contiguous S region.
    if (d < 512) {
        int xcd = d & 7, j = d >> 3;                       // j 0..63
        int bid = (2 * xcd + (j >> 5)) * 32 + (j & 31);    // b*32 + xt
        gemm_body<4096>(sp3, abf, u + UB3, bid, St);
    } else if (d < 640) {
        int e = d - 512;
        int xcd = e & 7, j = e >> 3;                       // j 0..15
        int bid = (2 * xcd + (j >> 3)) * 8 + (j & 7);
        gemm_body<1024>(sp4, abf + 327680, u + UB4, bid, St);
    } else {
        int e = d - 640;
        int xcd = e & 7, j = e >> 3;                       // j 0..3
        int bid = (2 * xcd + (j >> 1)) * 2 + (j & 1);
        gemm_body<256>(sp5, abf + 655360, u + UB5, bid, St);
    }
}

// ---------------- 5) combine: out[oh][ow] = sum_{kh,kw} V[(oh+kh)*H+ow+kw][kh*8+kw] ----------------
__global__ __launch_bounds__(256) void combine_kernel(const short* __restrict__ U,
                                                      float* __restrict__ out) {
    int tid = blockIdx.x * 256 + threadIdx.x;
    if (tid < 51984) {
        int b = tid / 3249, r = tid % 3249;
        int oh = r / 57, ow = r % 57;
        const short* u = U + UB3 + ((size_t)b * 4096 + oh * 64 + ow) * 64;
        float s = 0.0f;
#pragma unroll
        for (int kh = 0; kh < 8; ++kh)
#pragma unroll
            for (int kw = 0; kw < 8; ++kw)
                s += bf2f((unsigned short)u[(kh * 64 + kw) * 64 + kh * 8 + kw]);
        out[tid] = s;
    } else if (tid < 61984) {
        int x = tid - 51984;
        int b = x / 625, r = x % 625;
        int oh = r / 25, ow = r % 25;
        const short* u = U + UB4 + ((size_t)b * 1024 + oh * 32 + ow) * 64;
        float s = 0.0f;
#pragma unroll
        for (int kh = 0; kh < 8; ++kh)
#pragma unroll
            for (int kw = 0; kw < 8; ++kw)
                s += bf2f((unsigned short)u[(kh * 32 + kw) * 64 + kh * 8 + kw]);
        out[tid] = s;
    } else if (tid < 63280) {
        int x = tid - 61984;
        int b = x / 81, r = x % 81;
        int oh = r / 9, ow = r % 9;
        const short* u = U + UB5 + ((size_t)b * 256 + oh * 16 + ow) * 64;
        float s = 0.0f;
#pragma unroll
        for (int kh = 0; kh < 8; ++kh)
#pragma unroll
            for (int kw = 0; kw < 8; ++kw)
                s += bf2f((unsigned short)u[(kh * 16 + kw) * 64 + kh * 8 + kw]);
        out[tid] = s;
    }
}

extern "C" void kernel_launch(void* const* d_in, const int* in_sizes, int n_in,
                              void* d_out, int out_size, void* d_ws, size_t ws_size,
                              hipStream_t stream) {
    const float* t0p3 = (const float*)d_in[0];
    const float* t0p4 = (const float*)d_in[1];
    const float* t0p5 = (const float*)d_in[2];
    const float* t1p3 = (const float*)d_in[3];
    const float* t1p4 = (const float*)d_in[4];
    const float* t1p5 = (const float*)d_in[5];
    const float* t2p3 = (const float*)d_in[6];
    const float* t2p4 = (const float*)d_in[7];
    const float* t2p5 = (const float*)d_in[8];
    const float* sp3  = (const float*)d_in[9];
    const float* sp4  = (const float*)d_in[10];
    const float* sp5  = (const float*)d_in[11];
    const float* f3w1 = (const float*)d_in[12];
    const float* f3b1 = (const float*)d_in[13];
    const float* f3w2 = (const float*)d_in[14];
    const float* f3b2 = (const float*)d_in[15];
    const float* f4w1 = (const float*)d_in[16];
    const float* f4b1 = (const float*)d_in[17];
    const float* f4w2 = (const float*)d_in[18];
    const float* f4b2 = (const float*)d_in[19];
    const float* f5w1 = (const float*)d_in[20];
    const float* f5b1 = (const float*)d_in[21];
    const float* f5w2 = (const float*)d_in[22];
    const float* f5b2 = (const float*)d_in[23];

    float* ws = (float*)d_ws;
    short* abf = (short*)(ws + WS_ABF);
    short* ubuf = (short*)ws;

    prep_kernel<<<11520, 256, 0, stream>>>(t0p3, t1p3, t2p3, t0p4, t1p4, t2p4,
                                           t0p5, t1p5, t2p5,
                                           ws + WS_POOL3, ws + WS_POOL4, ws + WS_MEANS);
    weights_kernel<<<48, 256, 0, stream>>>(ws + WS_MEANS,
                                           f3w1, f3b1, f3w2, f3b2,
                                           f4w1, f4b1, f4w2, f4b2,
                                           f5w1, f5b1, f5w2, f5b2, ws + WS_AW);
    fuse_kernel<<<3840, 256, 0, stream>>>(ws + WS_POOL3, ws + WS_POOL3 + PLSZ, ws + WS_POOL3 + 2 * PLSZ,
                                          ws + WS_POOL4, ws + WS_POOL4 + PLSZ, ws + WS_POOL4 + 2 * PLSZ,
                                          t0p5, t1p5, t2p5,
                                          ws + WS_AW, ws + WS_TF, ws + WS_PART);
    atrans_kernel<<<240, 256, 0, stream>>>(ws + WS_TF, ws + WS_PART, abf);
    gemm_kernel<<<672, 256, 0, stream>>>(sp3, sp4, sp5, abf, ubuf);
    combine_kernel<<<248, 256, 0, stream>>>(ubuf, (float*)d_out);
}